// Round 15
// baseline (1511.405 us; speedup 1.0000x reference)
//
#include <hip/hip_runtime.h>
#include <hip/hip_cooperative_groups.h>
#include <stdint.h>
#include <math.h>

#define M_TOT 785664
#define NPRE  6000
#define NPOST 300
#define CAP   8192
#define NWORDS 94
#define ROWW   96
#define NPAD   6016

namespace cg = cooperative_groups;

__device__ __forceinline__ uint32_t okey(float f) {
    uint32_t u = __float_as_uint(f);
    return (u & 0x80000000u) ? ~u : (u | 0x80000000u);
}

// ---------------- zero init (hist/subhist/ctrl/degmask) + weight transpose ----------------
__global__ void k_init(const float* __restrict__ w1, float* __restrict__ wt,
                       uint32_t* __restrict__ p, int zn) {
    int i = blockIdx.x * 256 + threadIdx.x;
    if (i < zn) p[i] = 0u;
    if (i < 128 * 128 * 9) {
        int co = i / 1152; int r = i % 1152; int ci = r / 9; int tap = r % 9;
        wt[ci * 1152 + tap * 128 + co] = w1[i];
    }
}

// ---------------- fused conv3x3+ReLU + 1x1 heads, all levels ----------------
// BYTE-EXACT R11/R14 kernel: 746 us, VGPR 64 (cliff at >64). Do not perturb.
__global__ __launch_bounds__(512) void k_conv(
    const float* __restrict__ x0, const float* __restrict__ x1,
    const float* __restrict__ x2, const float* __restrict__ x3,
    const float* __restrict__ x4,
    const float* __restrict__ wt, const float* __restrict__ b1,
    const float* __restrict__ wobj, const float* __restrict__ bobj,
    const float* __restrict__ wbbx, const float* __restrict__ bbbx,
    float* __restrict__ sc, float* __restrict__ dl)
{
    __shared__ __attribute__((aligned(16))) float sx[8][18][20];
    __shared__ __attribute__((aligned(16))) float sw[8 * 9 * 128];

    int b = blockIdx.x, L = 0;
    if (b >= 512) { b -= 512; L = 1;
        if (b >= 128) { b -= 128; L = 2;
            if (b >= 32) { b -= 32; L = 3;
                if (b >= 8) { b -= 8; L = 4; } } } }
    const float* xs = (L == 0) ? x0 : (L == 1) ? x1 : (L == 2) ? x2 : (L == 3) ? x3 : x4;
    const int scoff_[5] = {0, 589824, 737280, 774144, 783360};
    int Wl = 256 >> L; int Hl = Wl; int HW = Wl * Wl;
    int tpiSh = 8 - 2 * L;
    int n  = b >> tpiSh;
    int r  = b & ((1 << tpiSh) - 1);
    int txSh = 4 - L;
    int ty0 = r >> txSh, tx0 = r & ((1 << txSh) - 1);
    int y0 = ty0 << 4, x0c = tx0 << 4;
    const float* xin = xs + (size_t)n * 128 * HW;

    int t = threadIdx.x;
    int tx = t & 15;
    int ty = t >> 4;
    int py = ty >> 1, px = (ty & 1) << 3;

    float acc0[4][8], acc1[4][8];
#pragma unroll
    for (int c = 0; c < 4; ++c)
#pragma unroll
        for (int e = 0; e < 8; ++e) { acc0[c][e] = 0.f; acc1[c][e] = 0.f; }

    for (int cc0 = 0; cc0 < 128; cc0 += 8) {
        __syncthreads();
        for (int i = t; i < 2880; i += 512) {
            int ci = i / 360; int rm = i % 360; int rr = rm / 20; int cc = rm % 20;
            float v = 0.f;
            int gy = y0 - 1 + rr, gx = x0c - 1 + cc;
            if (cc < 18 && gy >= 0 && gy < Hl && gx >= 0 && gx < Wl)
                v = xin[(size_t)(cc0 + ci) * HW + (size_t)gy * Wl + gx];
            sx[ci][rr][cc] = v;
        }
        {
            const float4* wsrc = (const float4*)(wt + (size_t)cc0 * 1152);
            float4* wdst = (float4*)sw;
            for (int i = t; i < 2304; i += 512) wdst[i] = wsrc[i];
        }
        __syncthreads();

#pragma unroll 1
        for (int ci = 0; ci < 8; ++ci) {
#pragma unroll
            for (int dy = 0; dy < 3; ++dy) {
                const float* xr = &sx[ci][py + dy][px];
                float4 xa = *(const float4*)(xr);
                float4 xb = *(const float4*)(xr + 4);
                float4 xc = *(const float4*)(xr + 8);
                float win[12] = {xa.x, xa.y, xa.z, xa.w, xb.x, xb.y, xb.z, xb.w,
                                 xc.x, xc.y, xc.z, xc.w};
#pragma unroll
                for (int dx = 0; dx < 3; ++dx) {
                    const float* wr = &sw[(ci * 9 + dy * 3 + dx) * 128 + tx * 4];
                    float4 wa = *(const float4*)(wr);
                    float4 wb = *(const float4*)(wr + 64);
                    float wva[4] = {wa.x, wa.y, wa.z, wa.w};
                    float wvb[4] = {wb.x, wb.y, wb.z, wb.w};
#pragma unroll
                    for (int e = 0; e < 8; ++e) {
                        float xv = win[e + dx];
#pragma unroll
                        for (int c = 0; c < 4; ++c) {
                            acc0[c][e] = fmaf(wva[c], xv, acc0[c][e]);
                            acc1[c][e] = fmaf(wvb[c], xv, acc1[c][e]);
                        }
                    }
                }
            }
        }
    }

    // bias + relu
#pragma unroll
    for (int c = 0; c < 4; ++c) {
        float ba = b1[tx * 4 + c];
        float bb = b1[64 + tx * 4 + c];
#pragma unroll
        for (int e = 0; e < 8; ++e) {
            float v0 = acc0[c][e] + ba;
            float v1 = acc1[c][e] + bb;
            acc0[c][e] = v0 > 0.f ? v0 : 0.f;
            acc1[c][e] = v1 > 0.f ? v1 : 0.f;
        }
    }

    // heads: 9 obj + 36 bbx; reduce over co via 16-lane xor butterfly
    int gy = y0 + py;
    size_t ppos = (size_t)gy * Wl + x0c + px;
    size_t scbase = (size_t)n * M_TOT + scoff_[L];
    size_t dlbase = (size_t)n * 4 * (size_t)M_TOT + 4 * (size_t)scoff_[L];
    for (int a = 0; a < 45; ++a) {
        const float* wp = (a < 9) ? (wobj + (size_t)a * 128) : (wbbx + (size_t)(a - 9) * 128);
        float4 wa = *(const float4*)(wp + tx * 4);
        float4 wb = *(const float4*)(wp + 64 + tx * 4);
        float wva[4] = {wa.x, wa.y, wa.z, wa.w};
        float wvb[4] = {wb.x, wb.y, wb.z, wb.w};
        float p[8];
#pragma unroll
        for (int e = 0; e < 8; ++e) p[e] = 0.f;
#pragma unroll
        for (int c = 0; c < 4; ++c)
#pragma unroll
            for (int e = 0; e < 8; ++e) {
                p[e] = fmaf(wva[c], acc0[c][e], p[e]);
                p[e] = fmaf(wvb[c], acc1[c][e], p[e]);
            }
#pragma unroll
        for (int mm = 1; mm < 16; mm <<= 1)
#pragma unroll
            for (int e = 0; e < 8; ++e)
                p[e] += __shfl_xor(p[e], mm, 64);
        if (tx == 0) {
            float bias = (a < 9) ? bobj[a] : bbbx[a - 9];
            float4 o0 = make_float4(p[0] + bias, p[1] + bias, p[2] + bias, p[3] + bias);
            float4 o1 = make_float4(p[4] + bias, p[5] + bias, p[6] + bias, p[7] + bias);
            float* dst = (a < 9) ? (sc + scbase + (size_t)a * HW + ppos)
                                 : (dl + dlbase + (size_t)(a - 9) * HW + ppos);
            *(float4*)dst = o0;
            *(float4*)(dst + 4) = o1;
        }
    }
}

// ---------------- scan helper (byte-same logic as k_scan) ----------------
__device__ void scan_phase(const uint32_t* h, uint32_t* c, int phase, uint32_t* tp) {
    int t = threadIdx.x;
    uint32_t s = 0;
    for (int r = 0; r < 32; ++r) s += h[8191 - (t * 32 + r)];
    tp[t] = s;
    __syncthreads();
    if (t == 0) {
        uint32_t run = (phase == 0) ? 0u : c[1];
        for (int i = 0; i < 256; ++i) { uint32_t v = tp[i]; tp[i] = run; run += v; }
    }
    __syncthreads();
    uint32_t cum = tp[t];
    for (int r = 0; r < 32; ++r) {
        int j = 8191 - (t * 32 + r);
        uint32_t cc = h[j];
        if (cum < 6000u && cum + cc >= 6000u) {
            if (phase == 0) { c[0] = (uint32_t)j; c[1] = cum; }
            else            { c[2] = (c[0] << 19) | ((uint32_t)j << 6); }
        }
        cum += cc;
    }
}

// ---------------- fused selection tail: hist..nms, one cooperative kernel ----------------
// grid = 512 x 256. Phase bodies are byte-faithful copies of R14's kernels.
__global__ __launch_bounds__(256) void k_select(
    const float* __restrict__ sc, uint32_t* __restrict__ hist,
    uint32_t* __restrict__ subh, uint32_t* __restrict__ ctrl,
    uint64_t* __restrict__ cand, uint64_t* __restrict__ sorted,
    const float* __restrict__ dl, const int* __restrict__ vsz,
    float* __restrict__ boxes, unsigned long long* __restrict__ degm,
    uint64_t* __restrict__ ioum, float* __restrict__ out)
{
    __shared__ __attribute__((aligned(16))) unsigned char smem[32768];
    cg::grid_group grid = cg::this_grid();
    const int bid = blockIdx.x;
    const int t = threadIdx.x;
    const int scoff_[5] = {0, 589824, 737280, 774144, 783360};

    // ---- Phase A: histogram (256 blocks per image; identical to k_hist) ----
    {
        uint32_t* lh = (uint32_t*)smem;
        int n = bid >> 8;
        for (int i = t; i < 8192; i += 256) lh[i] = 0u;
        __syncthreads();
        const float* s = sc + (size_t)n * M_TOT;
        for (int i = (bid & 255) * 256 + t; i < M_TOT; i += 256 * 256)
            atomicAdd(&lh[okey(s[i]) >> 19], 1u);
        __syncthreads();
        for (int i = t; i < 8192; i += 256) {
            uint32_t v = lh[i];
            if (v) atomicAdd(&hist[n * 8192 + i], v);
        }
    }
    grid.sync();

    // ---- Phase B: scan0 ----
    if (bid < 2) scan_phase(hist + bid * 8192, ctrl + bid * 8, 0, (uint32_t*)smem);
    grid.sync();

    // ---- Phase C: subhist ----
    {
        int stride = 512 * 256;
        for (int i = bid * 256 + t; i < 2 * M_TOT; i += stride) {
            int n = i >= M_TOT;
            uint32_t k = okey(sc[i]);
            if ((k >> 19) == ctrl[n * 8 + 0])
                atomicAdd(&subh[n * 8192 + ((k >> 6) & 0x1FFFu)], 1u);
        }
    }
    grid.sync();

    // ---- Phase D: scan1 ----
    if (bid < 2) scan_phase(subh + bid * 8192, ctrl + bid * 8, 1, (uint32_t*)smem);
    grid.sync();

    // ---- Phase E: compact (wave-aggregated slot alloc) ----
    {
        int stride = 512 * 256;
        int lane = t & 63;
        for (int i = bid * 256 + t; i < 2 * M_TOT; i += stride) {
            int n = i >= M_TOT;
            int q = n ? (i - M_TOT) : i;
            uint32_t k = okey(sc[i]);
            bool hit = (k >= ctrl[n * 8 + 2]);
            unsigned long long m = __ballot(hit);
            if (m) {
                int leader = __builtin_ctzll(m);
                uint32_t base = 0;
                if (lane == leader) base = atomicAdd(&ctrl[n * 8 + 3], (uint32_t)__popcll(m));
                base = (uint32_t)__shfl((int)base, leader, 64);
                if (hit) {
                    uint32_t slot = base + (uint32_t)__popcll(m & ((1ull << lane) - 1ull));
                    if (slot < CAP) {
                        int Lq = (q < 589824) ? 0 : (q < 737280) ? 1 : (q < 774144) ? 2
                                : (q < 783360) ? 3 : 4;
                        int r = q - scoff_[Lq];
                        int sh = 16 - 2 * Lq;
                        int a = r >> sh;
                        int pos = r & ((1 << sh) - 1);
                        uint32_t mm = (uint32_t)(scoff_[Lq] + pos * 9 + a);
                        cand[(size_t)n * CAP + slot] = ((uint64_t)k << 32) | (uint32_t)(~mm);
                    }
                }
            }
        }
    }
    grid.sync();

    // ---- Phase F: rank sort (64 block-units; identical to k_rank) ----
    if (bid < 64) {
        uint64_t* chunk = (uint64_t*)smem;
        int n = bid >> 5;
        uint32_t cnt = ctrl[n * 8 + 3];
        if (cnt > CAP) cnt = CAP;
        const uint64_t* cb = cand + (size_t)n * CAP;
        uint64_t* sb = sorted + (size_t)n * CAP;
        int i = (bid & 31) * 256 + t;
        uint64_t key = (i < (int)cnt) ? cb[i] : 0ull;
        uint32_t rank = 0;
        const ulonglong2* cb2 = (const ulonglong2*)cb;
        for (uint32_t base = 0; base < cnt; base += 2048) {
            __syncthreads();
            for (int j = t; j < 1024; j += 256)
                ((ulonglong2*)chunk)[j] = cb2[(base >> 1) + j];
            __syncthreads();
            uint32_t lim = cnt - base; if (lim > 2048u) lim = 2048u;
            for (uint32_t j = 0; j < lim; ++j) rank += (chunk[j] > key) ? 1u : 0u;
        }
        if (i < (int)cnt && rank < CAP) sb[rank] = key;
    }
    grid.sync();

    // ---- Phase G: decode + degenerate bitmask (identical to k_decode) ----
    {
        int i = bid * 256 + t;
        if (i < 2 * NPRE) {
            int n = i / NPRE, rk = i % NPRE;
            uint64_t pk = sorted[(size_t)n * CAP + rk];
            uint32_t m = ~(uint32_t)(pk & 0xFFFFFFFFull);
            int Lq = (m < 589824u) ? 0 : (m < 737280u) ? 1 : (m < 774144u) ? 2
                    : (m < 783360u) ? 3 : 4;
            int r = (int)m - scoff_[Lq];
            int pos = r / 9;
            int a = r - pos * 9;
            int Wl = 256 >> Lq;
            int y = pos >> (8 - Lq);
            int xx = pos & (Wl - 1);
            float stridef = (float)(4 << Lq);
            double sD = (double)(2 << (a / 3));
            double rD = ((a % 3) == 0) ? 0.5 : ((a % 3) == 1) ? 1.0 : 2.0;
            double hD = ((double)stridef * sD) * sqrt(rD);
            double wD = ((double)stridef * sD) * sqrt(1.0 / rD);
            double cD = (double)stridef / 2.0;
            float y1b = (float)(cD - hD / 2.0);
            float x1b = (float)(cD - wD / 2.0);
            float y2b = (float)(cD + hD / 2.0);
            float x2b = (float)(cD + wD / 2.0);
            float gy = (float)y * stridef;
            float gx = (float)xx * stridef;
            float ay1 = __fadd_rn(y1b, gy), ax1 = __fadd_rn(x1b, gx);
            float ay2 = __fadd_rn(y2b, gy), ax2 = __fadd_rn(x2b, gx);
            float cy = __fmul_rn(__fadd_rn(ay1, ay2), 0.5f);
            float cx = __fmul_rn(__fadd_rn(ax1, ax2), 0.5f);
            float ah = __fsub_rn(ay2, ay1);
            float aw = __fsub_rn(ax2, ax1);
            size_t HWl = (size_t)Wl * Wl;
            size_t db = (size_t)n * 4 * M_TOT + 4 * (size_t)scoff_[Lq] + (size_t)pos;
            float dy_ = dl[db + (size_t)(a * 4 + 0) * HWl];
            float dx_ = dl[db + (size_t)(a * 4 + 1) * HWl];
            float dh_ = dl[db + (size_t)(a * 4 + 2) * HWl];
            float dw_ = dl[db + (size_t)(a * 4 + 3) * HWl];
            float yo = __fadd_rn(cy, __fmul_rn(dy_, ah));
            float xo = __fadd_rn(cx, __fmul_rn(dx_, aw));
            const float SCLIPf = 4.135166556742356f;
            float ho = __fmul_rn(ah, (float)exp((double)fminf(dh_, SCLIPf)));
            float wo = __fmul_rn(aw, (float)exp((double)fminf(dw_, SCLIPf)));
            float hf = (float)vsz[n * 2 + 0], wf = (float)vsz[n * 2 + 1];
            float y1 = fminf(fmaxf(__fsub_rn(yo, __fmul_rn(0.5f, ho)), 0.f), hf);
            float x1 = fminf(fmaxf(__fsub_rn(xo, __fmul_rn(0.5f, wo)), 0.f), wf);
            float y2 = fminf(fmaxf(__fadd_rn(yo, __fmul_rn(0.5f, ho)), 0.f), hf);
            float x2 = fminf(fmaxf(__fadd_rn(xo, __fmul_rn(0.5f, wo)), 0.f), wf);
            *(float4*)(boxes + ((size_t)n * NPAD + rk) * 4) = make_float4(y1, x1, y2, x2);
            float area = __fmul_rn(__fsub_rn(y2, y1), __fsub_rn(x2, x1));
            float selfiou = __fdiv_rn(area, __fadd_rn(area, 1e-9f));
            if (!(selfiou > 0.7f))
                atomicOr(&degm[(size_t)n * ROWW + (rk >> 6)], 1ull << (rk & 63));
        }
    }
    grid.sync();

    // ---- Phase H: IoU bitmask matrix (grid-stride over (1500 x 2) blocks) ----
    {
        int lane = t & 63;
        for (int pair = bid; pair < 3000; pair += 512) {
            int n = pair >= 1500;
            int blk = pair - n * 1500;
            int i = blk * 4 + (t >> 6);
            const float* bsrc = boxes + (size_t)n * NPAD * 4;
            float4 bi = *(const float4*)(bsrc + (size_t)i * 4);
            float ai = __fmul_rn(__fsub_rn(bi.z, bi.x), __fsub_rn(bi.w, bi.y));
            uint64_t* row = ioum + ((size_t)n * NPAD + i) * ROWW;
            int w0 = i >> 6;
            for (int w = lane; w < w0; w += 64) row[w] = 0ull;
            for (int w = w0; w < NWORDS; ++w) {
                int j = (w << 6) | lane;
                bool pred = false;
                if (j > i && j < NPRE) {
                    float4 bj = *(const float4*)(bsrc + (size_t)j * 4);
                    float aj = __fmul_rn(__fsub_rn(bj.z, bj.x), __fsub_rn(bj.w, bj.y));
                    float ty = fmaxf(bi.x, bj.x), tx2 = fmaxf(bi.y, bj.y);
                    float by = fminf(bi.z, bj.z), bx2 = fminf(bi.w, bj.w);
                    float ih = fmaxf(__fsub_rn(by, ty), 0.f), iw = fmaxf(__fsub_rn(bx2, tx2), 0.f);
                    float inter = __fmul_rn(ih, iw);
                    float den = __fadd_rn(__fsub_rn(__fadd_rn(ai, aj), inter), 1e-9f);
                    float iou = __fdiv_rn(inter, den);
                    pred = iou > 0.7f;
                }
                unsigned long long msk = __ballot(pred);
                if (lane == 0) row[w] = (uint64_t)msk;
            }
        }
    }
    grid.sync();

    // ---- Phase I: greedy NMS (blocks 0,1; wave 0 of each; identical to k_nms) ----
    if (bid < 2 && t < 64) {
        uint64_t* sup = (uint64_t*)smem;                 // 752 B
        uint64_t* deg = (uint64_t*)(smem + 768);         // 752 B
        int* keepl = (int*)(smem + 1536);                // 1200 B
        int n = bid;
        int lane = t;
        for (int w = lane; w < NWORDS; w += 64) {
            sup[w] = 0ull;
            deg[w] = degm[(size_t)n * ROWW + w];
        }
        __builtin_amdgcn_s_barrier();
        int kept = 0;
        bool stop = false;
        for (int w = 0; w < NWORDS && kept < NPOST && !stop; ++w) {
            uint64_t vmask = (w == NWORDS - 1) ? ((1ull << 48) - 1ull) : ~0ull;
            uint64_t avail = (~sup[w]) & vmask;
            while (avail && kept < NPOST) {
                int bpos = __builtin_ctzll(avail);
                int i = (w << 6) | bpos;
                const uint64_t* row = ioum + ((size_t)n * NPAD + i) * ROWW;
                uint64_t r0 = row[lane];
                uint64_t r1 = (lane < NWORDS - 64) ? row[64 + lane] : 0ull;
                if (lane == 0) keepl[kept] = i;
                kept++;
                if ((deg[w] >> bpos) & 1ull) {
                    if (lane == 0) { for (int k2 = kept; k2 < NPOST; ++k2) keepl[k2] = i; }
                    kept = NPOST;
                    stop = true;
                    break;
                }
                sup[lane] |= r0;
                if (lane < NWORDS - 64) sup[64 + lane] |= r1;
                avail = (~sup[w]) & vmask & ~((2ull << bpos) - 1ull);
            }
        }
        for (int k = lane; k < NPOST; k += 64) {
            float4 bx = make_float4(0.f, 0.f, 0.f, 0.f);
            float vf = 0.f;
            if (k < kept) {
                int i = keepl[k];
                bx = *(const float4*)(boxes + ((size_t)n * NPAD + i) * 4);
                vf = 1.f;
            }
            *(float4*)(out + (size_t)n * 1200 + (size_t)k * 4) = bx;
            out[2400 + n * 300 + k] = vf;
        }
    }
}

extern "C" void kernel_launch(void* const* d_in, const int* in_sizes, int n_in,
                              void* d_out, int out_size, void* d_ws, size_t ws_size,
                              hipStream_t stream) {
    (void)out_size; (void)ws_size;
    static const int want[12] = {16777216, 4194304, 1048576, 262144, 65536,
                                 147456, 128, 1152, 9, 4608, 36, 4};
    const void* p[12];
    for (int k = 0; k < 12; ++k) p[k] = d_in[k];
    bool pos_ok = (n_in >= 12);
    for (int k = 0; k < 12 && pos_ok; ++k) if (in_sizes[k] != want[k]) pos_ok = false;
    if (!pos_ok) {
        for (int k = 0; k < 12; ++k)
            for (int j = 0; j < n_in; ++j)
                if (in_sizes[j] == want[k]) { p[k] = d_in[j]; break; }
    }
    const float* x0   = (const float*)p[0];
    const float* x1   = (const float*)p[1];
    const float* x2   = (const float*)p[2];
    const float* x3   = (const float*)p[3];
    const float* x4   = (const float*)p[4];
    const float* w1   = (const float*)p[5];
    const float* b1   = (const float*)p[6];
    const float* wobj = (const float*)p[7];
    const float* bobj = (const float*)p[8];
    const float* wbbx = (const float*)p[9];
    const float* bbbx = (const float*)p[10];
    const int*   vsz  = (const int*)p[11];
    float* out = (float*)d_out;

    size_t off = 0;
    char* base = (char*)d_ws;
    auto carve = [&](size_t bytes) -> void* {
        void* q = base + off;
        off += (bytes + 255) & ~(size_t)255;
        return q;
    };
    float*    SC     = (float*)carve((size_t)2 * M_TOT * 4);
    float*    DL     = (float*)carve((size_t)2 * M_TOT * 16);
    float*    WT     = (float*)carve((size_t)147456 * 4);
    uint32_t* HIST   = (uint32_t*)carve((size_t)16384 * 4);
    uint32_t* SUBH   = (uint32_t*)carve((size_t)16384 * 4);
    uint32_t* CTRL   = (uint32_t*)carve((size_t)64 * 4);
    unsigned long long* DEGM = (unsigned long long*)carve((size_t)2 * ROWW * 8);
    uint64_t* CAND   = (uint64_t*)carve((size_t)2 * CAP * 8);
    uint64_t* SORTED = (uint64_t*)carve((size_t)2 * CAP * 8);
    float*    BOXES  = (float*)carve((size_t)2 * NPAD * 16);
    uint64_t* IOUM   = (uint64_t*)carve((size_t)2 * NPAD * ROWW * 8);

    int zn = (int)(((char*)CAND - (char*)HIST) / 4);  // hist+subhist+ctrl+degm contiguous
    int initN = (zn > 147456) ? zn : 147456;
    k_init<<<(initN + 255) / 256, 256, 0, stream>>>(w1, WT, HIST, zn);
    k_conv<<<682, 512, 0, stream>>>(x0, x1, x2, x3, x4, WT, b1,
                                    wobj, bobj, wbbx, bbbx, SC, DL);
    {
        void* kargs[12] = {
            (void*)&SC, (void*)&HIST, (void*)&SUBH, (void*)&CTRL,
            (void*)&CAND, (void*)&SORTED, (void*)&DL, (void*)&vsz,
            (void*)&BOXES, (void*)&DEGM, (void*)&IOUM, (void*)&out
        };
        hipLaunchCooperativeKernel((const void*)k_select, dim3(512), dim3(256),
                                   kargs, 0, stream);
    }
}

// Round 16
// 1038.518 us; speedup vs baseline: 1.4553x; 1.4553x over previous
//
#include <hip/hip_runtime.h>
#include <stdint.h>
#include <math.h>

#define M_TOT 785664
#define NPRE  6000
#define NPOST 300
#define CAP   8192
#define NWORDS 94
#define ROWW   96
#define NPAD   6016

__device__ __forceinline__ uint32_t okey(float f) {
    uint32_t u = __float_as_uint(f);
    return (u & 0x80000000u) ? ~u : (u | 0x80000000u);
}

// ---------------- zero init (hist/subhist/ctrl/degmask) + weight transpose ----------------
__global__ void k_init(const float* __restrict__ w1, float* __restrict__ wt,
                       uint32_t* __restrict__ p, int zn) {
    int i = blockIdx.x * 256 + threadIdx.x;
    if (i < zn) p[i] = 0u;
    if (i < 128 * 128 * 9) {
        int co = i / 1152; int r = i % 1152; int ci = r / 9; int tap = r % 9;
        wt[ci * 1152 + tap * 128 + co] = w1[i];
    }
}

// ---------------- fused conv3x3+ReLU + 1x1 heads, all levels ----------------
// BYTE-EXACT R11/R14 kernel: 746 us, VGPR 64 (cliff at >64: waves/SIMD halve),
// absmax 0.0. Structural plateau — 7 intra-structure levers all null/negative.
__global__ __launch_bounds__(512) void k_conv(
    const float* __restrict__ x0, const float* __restrict__ x1,
    const float* __restrict__ x2, const float* __restrict__ x3,
    const float* __restrict__ x4,
    const float* __restrict__ wt, const float* __restrict__ b1,
    const float* __restrict__ wobj, const float* __restrict__ bobj,
    const float* __restrict__ wbbx, const float* __restrict__ bbbx,
    float* __restrict__ sc, float* __restrict__ dl)
{
    __shared__ __attribute__((aligned(16))) float sx[8][18][20];
    __shared__ __attribute__((aligned(16))) float sw[8 * 9 * 128];

    int b = blockIdx.x, L = 0;
    if (b >= 512) { b -= 512; L = 1;
        if (b >= 128) { b -= 128; L = 2;
            if (b >= 32) { b -= 32; L = 3;
                if (b >= 8) { b -= 8; L = 4; } } } }
    const float* xs = (L == 0) ? x0 : (L == 1) ? x1 : (L == 2) ? x2 : (L == 3) ? x3 : x4;
    const int scoff_[5] = {0, 589824, 737280, 774144, 783360};
    int Wl = 256 >> L; int Hl = Wl; int HW = Wl * Wl;
    int tpiSh = 8 - 2 * L;
    int n  = b >> tpiSh;
    int r  = b & ((1 << tpiSh) - 1);
    int txSh = 4 - L;
    int ty0 = r >> txSh, tx0 = r & ((1 << txSh) - 1);
    int y0 = ty0 << 4, x0c = tx0 << 4;
    const float* xin = xs + (size_t)n * 128 * HW;

    int t = threadIdx.x;
    int tx = t & 15;
    int ty = t >> 4;
    int py = ty >> 1, px = (ty & 1) << 3;

    float acc0[4][8], acc1[4][8];
#pragma unroll
    for (int c = 0; c < 4; ++c)
#pragma unroll
        for (int e = 0; e < 8; ++e) { acc0[c][e] = 0.f; acc1[c][e] = 0.f; }

    for (int cc0 = 0; cc0 < 128; cc0 += 8) {
        __syncthreads();
        for (int i = t; i < 2880; i += 512) {
            int ci = i / 360; int rm = i % 360; int rr = rm / 20; int cc = rm % 20;
            float v = 0.f;
            int gy = y0 - 1 + rr, gx = x0c - 1 + cc;
            if (cc < 18 && gy >= 0 && gy < Hl && gx >= 0 && gx < Wl)
                v = xin[(size_t)(cc0 + ci) * HW + (size_t)gy * Wl + gx];
            sx[ci][rr][cc] = v;
        }
        {
            const float4* wsrc = (const float4*)(wt + (size_t)cc0 * 1152);
            float4* wdst = (float4*)sw;
            for (int i = t; i < 2304; i += 512) wdst[i] = wsrc[i];
        }
        __syncthreads();

#pragma unroll 1
        for (int ci = 0; ci < 8; ++ci) {
#pragma unroll
            for (int dy = 0; dy < 3; ++dy) {
                const float* xr = &sx[ci][py + dy][px];
                float4 xa = *(const float4*)(xr);
                float4 xb = *(const float4*)(xr + 4);
                float4 xc = *(const float4*)(xr + 8);
                float win[12] = {xa.x, xa.y, xa.z, xa.w, xb.x, xb.y, xb.z, xb.w,
                                 xc.x, xc.y, xc.z, xc.w};
#pragma unroll
                for (int dx = 0; dx < 3; ++dx) {
                    const float* wr = &sw[(ci * 9 + dy * 3 + dx) * 128 + tx * 4];
                    float4 wa = *(const float4*)(wr);
                    float4 wb = *(const float4*)(wr + 64);
                    float wva[4] = {wa.x, wa.y, wa.z, wa.w};
                    float wvb[4] = {wb.x, wb.y, wb.z, wb.w};
#pragma unroll
                    for (int e = 0; e < 8; ++e) {
                        float xv = win[e + dx];
#pragma unroll
                        for (int c = 0; c < 4; ++c) {
                            acc0[c][e] = fmaf(wva[c], xv, acc0[c][e]);
                            acc1[c][e] = fmaf(wvb[c], xv, acc1[c][e]);
                        }
                    }
                }
            }
        }
    }

    // bias + relu
#pragma unroll
    for (int c = 0; c < 4; ++c) {
        float ba = b1[tx * 4 + c];
        float bb = b1[64 + tx * 4 + c];
#pragma unroll
        for (int e = 0; e < 8; ++e) {
            float v0 = acc0[c][e] + ba;
            float v1 = acc1[c][e] + bb;
            acc0[c][e] = v0 > 0.f ? v0 : 0.f;
            acc1[c][e] = v1 > 0.f ? v1 : 0.f;
        }
    }

    // heads: 9 obj + 36 bbx; reduce over co via 16-lane xor butterfly
    int gy = y0 + py;
    size_t ppos = (size_t)gy * Wl + x0c + px;
    size_t scbase = (size_t)n * M_TOT + scoff_[L];
    size_t dlbase = (size_t)n * 4 * (size_t)M_TOT + 4 * (size_t)scoff_[L];
    for (int a = 0; a < 45; ++a) {
        const float* wp = (a < 9) ? (wobj + (size_t)a * 128) : (wbbx + (size_t)(a - 9) * 128);
        float4 wa = *(const float4*)(wp + tx * 4);
        float4 wb = *(const float4*)(wp + 64 + tx * 4);
        float wva[4] = {wa.x, wa.y, wa.z, wa.w};
        float wvb[4] = {wb.x, wb.y, wb.z, wb.w};
        float p[8];
#pragma unroll
        for (int e = 0; e < 8; ++e) p[e] = 0.f;
#pragma unroll
        for (int c = 0; c < 4; ++c)
#pragma unroll
            for (int e = 0; e < 8; ++e) {
                p[e] = fmaf(wva[c], acc0[c][e], p[e]);
                p[e] = fmaf(wvb[c], acc1[c][e], p[e]);
            }
#pragma unroll
        for (int mm = 1; mm < 16; mm <<= 1)
#pragma unroll
            for (int e = 0; e < 8; ++e)
                p[e] += __shfl_xor(p[e], mm, 64);
        if (tx == 0) {
            float bias = (a < 9) ? bobj[a] : bbbx[a - 9];
            float4 o0 = make_float4(p[0] + bias, p[1] + bias, p[2] + bias, p[3] + bias);
            float4 o1 = make_float4(p[4] + bias, p[5] + bias, p[6] + bias, p[7] + bias);
            float* dst = (a < 9) ? (sc + scbase + (size_t)a * HW + ppos)
                                 : (dl + dlbase + (size_t)(a - 9) * HW + ppos);
            *(float4*)dst = o0;
            *(float4*)(dst + 4) = o1;
        }
    }
}

// ---------------- histogram (top 13 key bits), LDS-privatized ----------------
__global__ __launch_bounds__(256) void k_hist(const float* __restrict__ sc,
                                              uint32_t* __restrict__ hist) {
    __shared__ uint32_t lh[8192];
    int n = blockIdx.y;
    for (int i = threadIdx.x; i < 8192; i += 256) lh[i] = 0u;
    __syncthreads();
    const float* s = sc + (size_t)n * M_TOT;
    int stride = gridDim.x * 256;
    for (int i = blockIdx.x * 256 + threadIdx.x; i < M_TOT; i += stride)
        atomicAdd(&lh[okey(s[i]) >> 19], 1u);
    __syncthreads();
    for (int i = threadIdx.x; i < 8192; i += 256) {
        uint32_t v = lh[i];
        if (v) atomicAdd(&hist[n * 8192 + i], v);
    }
}

// ---------------- sub-histogram within boundary bucket (rare hits) ----------------
__global__ void k_subhist(const float* __restrict__ sc, const uint32_t* __restrict__ ctrl,
                          uint32_t* __restrict__ subh) {
    int i = blockIdx.x * blockDim.x + threadIdx.x;
    int stride = gridDim.x * blockDim.x;
    for (; i < 2 * M_TOT; i += stride) {
        int n = i >= M_TOT;
        uint32_t k = okey(sc[i]);
        if ((k >> 19) == ctrl[n * 8 + 0])
            atomicAdd(&subh[n * 8192 + ((k >> 6) & 0x1FFFu)], 1u);
    }
}

// ---------------- scan: find bucket crossing rank 6000 (descending) ----------------
__global__ void k_scan(const uint32_t* __restrict__ hist, uint32_t* __restrict__ ctrl, int phase) {
    int n = blockIdx.x;
    const uint32_t* h = hist + n * 8192;
    uint32_t* c = ctrl + n * 8;
    __shared__ uint32_t tp[256];
    int t = threadIdx.x;
    uint32_t s = 0;
    for (int r = 0; r < 32; ++r) s += h[8191 - (t * 32 + r)];
    tp[t] = s;
    __syncthreads();
    if (t == 0) {
        uint32_t run = (phase == 0) ? 0u : c[1];
        for (int i = 0; i < 256; ++i) { uint32_t v = tp[i]; tp[i] = run; run += v; }
    }
    __syncthreads();
    uint32_t cum = tp[t];
    for (int r = 0; r < 32; ++r) {
        int j = 8191 - (t * 32 + r);
        uint32_t cc = h[j];
        if (cum < 6000u && cum + cc >= 6000u) {
            if (phase == 0) { c[0] = (uint32_t)j; c[1] = cum; }
            else            { c[2] = (c[0] << 19) | ((uint32_t)j << 6); }
        }
        cum += cc;
    }
}

// ---------------- compact candidates (key >= T2), wave-aggregated slot alloc ----------------
__global__ void k_compact(const float* __restrict__ sc, uint32_t* __restrict__ ctrl,
                          uint64_t* __restrict__ cand) {
    int i = blockIdx.x * blockDim.x + threadIdx.x;
    int stride = gridDim.x * blockDim.x;
    const int scoff_[5] = {0, 589824, 737280, 774144, 783360};
    int lane = threadIdx.x & 63;
    for (; i < 2 * M_TOT; i += stride) {
        int n = i >= M_TOT;
        int q = n ? (i - M_TOT) : i;
        uint32_t k = okey(sc[i]);
        bool hit = (k >= ctrl[n * 8 + 2]);
        unsigned long long m = __ballot(hit);
        if (m) {
            int leader = __builtin_ctzll(m);
            uint32_t base = 0;
            if (lane == leader) base = atomicAdd(&ctrl[n * 8 + 3], (uint32_t)__popcll(m));
            base = (uint32_t)__shfl((int)base, leader, 64);
            if (hit) {
                uint32_t slot = base + (uint32_t)__popcll(m & ((1ull << lane) - 1ull));
                if (slot < CAP) {
                    int Lq = (q < 589824) ? 0 : (q < 737280) ? 1 : (q < 774144) ? 2
                            : (q < 783360) ? 3 : 4;
                    int r = q - scoff_[Lq];
                    int sh = 16 - 2 * Lq;
                    int a = r >> sh;
                    int pos = r & ((1 << sh) - 1);
                    uint32_t mm = (uint32_t)(scoff_[Lq] + pos * 9 + a);
                    cand[(size_t)n * CAP + slot] = ((uint64_t)k << 32) | (uint32_t)(~mm);
                }
            }
        }
    }
}

// ---------------- rank-based sort (keys unique); vectorized staging ----------------
__global__ __launch_bounds__(256) void k_rank(const uint64_t* __restrict__ cand,
                                              const uint32_t* __restrict__ ctrl,
                                              uint64_t* __restrict__ sorted) {
    __shared__ __attribute__((aligned(16))) uint64_t chunk[2048];
    int n = blockIdx.y;
    uint32_t cnt = ctrl[n * 8 + 3];
    if (cnt > CAP) cnt = CAP;
    const uint64_t* cb = cand + (size_t)n * CAP;
    uint64_t* sb = sorted + (size_t)n * CAP;
    int i = blockIdx.x * 256 + threadIdx.x;
    uint64_t key = (i < (int)cnt) ? cb[i] : 0ull;
    uint32_t rank = 0;
    const ulonglong2* cb2 = (const ulonglong2*)cb;
    for (uint32_t base = 0; base < cnt; base += 2048) {
        __syncthreads();
        for (int j = threadIdx.x; j < 1024; j += 256)
            ((ulonglong2*)chunk)[j] = cb2[(base >> 1) + j];
        __syncthreads();
        uint32_t lim = cnt - base; if (lim > 2048u) lim = 2048u;
        for (uint32_t j = 0; j < lim; ++j) rank += (chunk[j] > key) ? 1u : 0u;
    }
    if (i < (int)cnt && rank < CAP) sb[rank] = key;
}

// ---------------- decode top-6000 boxes + degenerate bitmask ----------------
__global__ void k_decode(const uint64_t* __restrict__ cand, const float* __restrict__ dl,
                         const int* __restrict__ vsz, float* __restrict__ boxes,
                         unsigned long long* __restrict__ degm) {
    int i = blockIdx.x * 256 + threadIdx.x;
    if (i >= 2 * NPRE) return;
    int n = i / NPRE, rk = i % NPRE;
    const int scoff_[5] = {0, 589824, 737280, 774144, 783360};
    uint64_t pk = cand[(size_t)n * CAP + rk];
    uint32_t m = ~(uint32_t)(pk & 0xFFFFFFFFull);
    int Lq = (m < 589824u) ? 0 : (m < 737280u) ? 1 : (m < 774144u) ? 2 : (m < 783360u) ? 3 : 4;
    int r = (int)m - scoff_[Lq];
    int pos = r / 9;
    int a = r - pos * 9;
    int Wl = 256 >> Lq;
    int y = pos >> (8 - Lq);
    int xx = pos & (Wl - 1);
    float stridef = (float)(4 << Lq);
    double sD = (double)(2 << (a / 3));
    double rD = ((a % 3) == 0) ? 0.5 : ((a % 3) == 1) ? 1.0 : 2.0;
    double hD = ((double)stridef * sD) * sqrt(rD);
    double wD = ((double)stridef * sD) * sqrt(1.0 / rD);
    double cD = (double)stridef / 2.0;
    float y1b = (float)(cD - hD / 2.0);
    float x1b = (float)(cD - wD / 2.0);
    float y2b = (float)(cD + hD / 2.0);
    float x2b = (float)(cD + wD / 2.0);
    float gy = (float)y * stridef;
    float gx = (float)xx * stridef;
    float ay1 = __fadd_rn(y1b, gy), ax1 = __fadd_rn(x1b, gx);
    float ay2 = __fadd_rn(y2b, gy), ax2 = __fadd_rn(x2b, gx);
    float cy = __fmul_rn(__fadd_rn(ay1, ay2), 0.5f);
    float cx = __fmul_rn(__fadd_rn(ax1, ax2), 0.5f);
    float ah = __fsub_rn(ay2, ay1);
    float aw = __fsub_rn(ax2, ax1);
    size_t HWl = (size_t)Wl * Wl;
    size_t db = (size_t)n * 4 * M_TOT + 4 * (size_t)scoff_[Lq] + (size_t)pos;
    float dy_ = dl[db + (size_t)(a * 4 + 0) * HWl];
    float dx_ = dl[db + (size_t)(a * 4 + 1) * HWl];
    float dh_ = dl[db + (size_t)(a * 4 + 2) * HWl];
    float dw_ = dl[db + (size_t)(a * 4 + 3) * HWl];
    float yo = __fadd_rn(cy, __fmul_rn(dy_, ah));
    float xo = __fadd_rn(cx, __fmul_rn(dx_, aw));
    const float SCLIPf = 4.135166556742356f;
    float ho = __fmul_rn(ah, (float)exp((double)fminf(dh_, SCLIPf)));
    float wo = __fmul_rn(aw, (float)exp((double)fminf(dw_, SCLIPf)));
    float hf = (float)vsz[n * 2 + 0], wf = (float)vsz[n * 2 + 1];
    float y1 = fminf(fmaxf(__fsub_rn(yo, __fmul_rn(0.5f, ho)), 0.f), hf);
    float x1 = fminf(fmaxf(__fsub_rn(xo, __fmul_rn(0.5f, wo)), 0.f), wf);
    float y2 = fminf(fmaxf(__fadd_rn(yo, __fmul_rn(0.5f, ho)), 0.f), hf);
    float x2 = fminf(fmaxf(__fadd_rn(xo, __fmul_rn(0.5f, wo)), 0.f), wf);
    *(float4*)(boxes + ((size_t)n * NPAD + rk) * 4) = make_float4(y1, x1, y2, x2);
    float area = __fmul_rn(__fsub_rn(y2, y1), __fsub_rn(x2, x1));
    float selfiou = __fdiv_rn(area, __fadd_rn(area, 1e-9f));
    if (!(selfiou > 0.7f))
        atomicOr(&degm[(size_t)n * ROWW + (rk >> 6)], 1ull << (rk & 63));
}

// ---------------- IoU bitmask matrix: row i, bit j set iff j>i and IoU>0.7 ----------------
__global__ __launch_bounds__(256) void k_iou(const float* __restrict__ boxes,
                                             uint64_t* __restrict__ ioum) {
    int n = blockIdx.y;
    int i = blockIdx.x * 4 + (threadIdx.x >> 6);
    int lane = threadIdx.x & 63;
    const float* bsrc = boxes + (size_t)n * NPAD * 4;
    float4 bi = *(const float4*)(bsrc + (size_t)i * 4);
    float ai = __fmul_rn(__fsub_rn(bi.z, bi.x), __fsub_rn(bi.w, bi.y));
    uint64_t* row = ioum + ((size_t)n * NPAD + i) * ROWW;
    int w0 = i >> 6;
    for (int w = lane; w < w0; w += 64) row[w] = 0ull;
    for (int w = w0; w < NWORDS; ++w) {
        int j = (w << 6) | lane;
        bool pred = false;
        if (j > i && j < NPRE) {
            float4 bj = *(const float4*)(bsrc + (size_t)j * 4);
            float aj = __fmul_rn(__fsub_rn(bj.z, bj.x), __fsub_rn(bj.w, bj.y));
            float ty = fmaxf(bi.x, bj.x), tx2 = fmaxf(bi.y, bj.y);
            float by = fminf(bi.z, bj.z), bx2 = fminf(bi.w, bj.w);
            float ih = fmaxf(__fsub_rn(by, ty), 0.f), iw = fmaxf(__fsub_rn(bx2, tx2), 0.f);
            float inter = __fmul_rn(ih, iw);
            float den = __fadd_rn(__fsub_rn(__fadd_rn(ai, aj), inter), 1e-9f);
            float iou = __fdiv_rn(inter, den);
            pred = iou > 0.7f;
        }
        unsigned long long msk = __ballot(pred);
        if (lane == 0) row[w] = (uint64_t)msk;
    }
}

// ---------------- greedy NMS scan; degeneracy via precomputed bitmask ----------------
__global__ __launch_bounds__(64) void k_nms(const float* __restrict__ boxes,
                                            const uint64_t* __restrict__ ioum,
                                            const unsigned long long* __restrict__ degm,
                                            float* __restrict__ out) {
    int n = blockIdx.x;
    __shared__ uint64_t sup[NWORDS];
    __shared__ uint64_t deg[NWORDS];
    __shared__ int keepl[NPOST];
    int lane = threadIdx.x;
    for (int w = lane; w < NWORDS; w += 64) {
        sup[w] = 0ull;
        deg[w] = degm[(size_t)n * ROWW + w];
    }
    __syncthreads();
    int kept = 0;
    bool stop = false;
    for (int w = 0; w < NWORDS && kept < NPOST && !stop; ++w) {
        uint64_t vmask = (w == NWORDS - 1) ? ((1ull << 48) - 1ull) : ~0ull;
        uint64_t avail = (~sup[w]) & vmask;
        while (avail && kept < NPOST) {
            int bpos = __builtin_ctzll(avail);
            int i = (w << 6) | bpos;
            const uint64_t* row = ioum + ((size_t)n * NPAD + i) * ROWW;
            uint64_t r0 = row[lane];
            uint64_t r1 = (lane < NWORDS - 64) ? row[64 + lane] : 0ull;
            if (lane == 0) keepl[kept] = i;
            kept++;
            if ((deg[w] >> bpos) & 1ull) {
                if (lane == 0) { for (int k2 = kept; k2 < NPOST; ++k2) keepl[k2] = i; }
                kept = NPOST;
                stop = true;
                break;
            }
            sup[lane] |= r0;
            if (lane < NWORDS - 64) sup[64 + lane] |= r1;
            __syncthreads();
            avail = (~sup[w]) & vmask & ~((2ull << bpos) - 1ull);
        }
    }
    __syncthreads();
    for (int k = lane; k < NPOST; k += 64) {
        float4 bx = make_float4(0.f, 0.f, 0.f, 0.f);
        float vf = 0.f;
        if (k < kept) {
            int i = keepl[k];
            bx = *(const float4*)(boxes + ((size_t)n * NPAD + i) * 4);
            vf = 1.f;
        }
        *(float4*)(out + (size_t)n * 1200 + (size_t)k * 4) = bx;
        out[2400 + n * 300 + k] = vf;
    }
}

extern "C" void kernel_launch(void* const* d_in, const int* in_sizes, int n_in,
                              void* d_out, int out_size, void* d_ws, size_t ws_size,
                              hipStream_t stream) {
    (void)out_size; (void)ws_size;
    static const int want[12] = {16777216, 4194304, 1048576, 262144, 65536,
                                 147456, 128, 1152, 9, 4608, 36, 4};
    const void* p[12];
    for (int k = 0; k < 12; ++k) p[k] = d_in[k];
    bool pos_ok = (n_in >= 12);
    for (int k = 0; k < 12 && pos_ok; ++k) if (in_sizes[k] != want[k]) pos_ok = false;
    if (!pos_ok) {
        for (int k = 0; k < 12; ++k)
            for (int j = 0; j < n_in; ++j)
                if (in_sizes[j] == want[k]) { p[k] = d_in[j]; break; }
    }
    const float* x0   = (const float*)p[0];
    const float* x1   = (const float*)p[1];
    const float* x2   = (const float*)p[2];
    const float* x3   = (const float*)p[3];
    const float* x4   = (const float*)p[4];
    const float* w1   = (const float*)p[5];
    const float* b1   = (const float*)p[6];
    const float* wobj = (const float*)p[7];
    const float* bobj = (const float*)p[8];
    const float* wbbx = (const float*)p[9];
    const float* bbbx = (const float*)p[10];
    const int*   vsz  = (const int*)p[11];
    float* out = (float*)d_out;

    size_t off = 0;
    char* base = (char*)d_ws;
    auto carve = [&](size_t bytes) -> void* {
        void* q = base + off;
        off += (bytes + 255) & ~(size_t)255;
        return q;
    };
    float*    SC     = (float*)carve((size_t)2 * M_TOT * 4);
    float*    DL     = (float*)carve((size_t)2 * M_TOT * 16);
    float*    WT     = (float*)carve((size_t)147456 * 4);
    uint32_t* HIST   = (uint32_t*)carve((size_t)16384 * 4);
    uint32_t* SUBH   = (uint32_t*)carve((size_t)16384 * 4);
    uint32_t* CTRL   = (uint32_t*)carve((size_t)64 * 4);
    unsigned long long* DEGM = (unsigned long long*)carve((size_t)2 * ROWW * 8);
    uint64_t* CAND   = (uint64_t*)carve((size_t)2 * CAP * 8);
    uint64_t* SORTED = (uint64_t*)carve((size_t)2 * CAP * 8);
    float*    BOXES  = (float*)carve((size_t)2 * NPAD * 16);
    uint64_t* IOUM   = (uint64_t*)carve((size_t)2 * NPAD * ROWW * 8);

    int zn = (int)(((char*)CAND - (char*)HIST) / 4);  // hist+subhist+ctrl+degm contiguous
    int initN = (zn > 147456) ? zn : 147456;
    k_init<<<(initN + 255) / 256, 256, 0, stream>>>(w1, WT, HIST, zn);
    k_conv<<<682, 512, 0, stream>>>(x0, x1, x2, x3, x4, WT, b1,
                                    wobj, bobj, wbbx, bbbx, SC, DL);
    k_hist<<<dim3(256, 2), 256, 0, stream>>>(SC, HIST);
    k_scan<<<2, 256, 0, stream>>>(HIST, CTRL, 0);
    k_subhist<<<1024, 256, 0, stream>>>(SC, CTRL, SUBH);
    k_scan<<<2, 256, 0, stream>>>(SUBH, CTRL, 1);
    k_compact<<<1024, 256, 0, stream>>>(SC, CTRL, CAND);
    k_rank<<<dim3(CAP / 256, 2), 256, 0, stream>>>(CAND, CTRL, SORTED);
    k_decode<<<(2 * NPRE + 255) / 256, 256, 0, stream>>>(SORTED, DL, vsz, BOXES, DEGM);
    k_iou<<<dim3(NPRE / 4, 2), 256, 0, stream>>>(BOXES, IOUM);
    k_nms<<<2, 64, 0, stream>>>(BOXES, IOUM, DEGM, out);
}